// Round 1
// baseline (74.503 us; speedup 1.0000x reference)
//
#include <hip/hip_runtime.h>
#include <hip/hip_bf16.h>
#include <stdint.h>

// PWB linear layer: out = relu(x @ q(W) + q(b)), q = round(clip(t,-1,1)*127)/127
// Strategy: quantize W -> bf16 Wt[N][K] (transposed), x -> bf16, b -> f32 in d_ws;
// then m97-structure bf16 MFMA GEMM (128x128 tile, BK=32, 4 waves, global_load_lds
// width-16, XOR k-chunk swizzle for bank-conflict-free ds_read_b128).

typedef __attribute__((ext_vector_type(8))) short bf16x8;
typedef __attribute__((ext_vector_type(4))) float f32x4;

#define BM 128
#define BN 128
#define BK 32

__device__ __forceinline__ unsigned short f2b_rne(float f) {
    union { float f; uint32_t u; } v; v.f = f;
    uint32_t u = v.u;
    return (unsigned short)((u + 0x7FFFu + ((u >> 16) & 1u)) >> 16);
}

__device__ __forceinline__ float pwb_q(float w) {
    w = fminf(fmaxf(w, -1.f), 1.f);
    return rintf(w * 127.f) * (1.f / 127.f);   // rintf = RNE, matches jnp.round
}

__device__ __forceinline__ void gload_lds16(const void* g, void* l) {
    __builtin_amdgcn_global_load_lds(
        (__attribute__((address_space(1))) void*)(g),
        (__attribute__((address_space(3))) void*)(l),
        16, 0, 0);
}

// ---- pre-pass: x fp32 -> bf16 (same layout) ----
__global__ void pwb_cvt_x(const float4* __restrict__ x, ushort4* __restrict__ xb, int n4) {
    int i = blockIdx.x * blockDim.x + threadIdx.x;
    if (i < n4) {
        float4 v = x[i];
        xb[i] = make_ushort4(f2b_rne(v.x), f2b_rne(v.y), f2b_rne(v.z), f2b_rne(v.w));
    }
}

// ---- pre-pass: W[DIN][DOUT] fp32 -> quantized, transposed Wt[DOUT][DIN] bf16 ----
__global__ void pwb_quant_w(const float* __restrict__ W, unsigned short* __restrict__ Wt,
                            int DIN, int DOUT) {
    __shared__ unsigned short t[32][33];
    const int tx = threadIdx.x;     // 32
    const int ty = threadIdx.y;     // 8
    const int c0 = blockIdx.x * 32; // DOUT base
    const int r0 = blockIdx.y * 32; // DIN base
#pragma unroll
    for (int i = 0; i < 4; ++i) {
        int row = r0 + ty + i * 8;
        float w = W[(size_t)row * DOUT + c0 + tx];
        t[tx][ty + i * 8] = f2b_rne(pwb_q(w));
    }
    __syncthreads();
#pragma unroll
    for (int i = 0; i < 4; ++i) {
        int orow = c0 + ty + i * 8; // DOUT index
        Wt[(size_t)orow * DIN + r0 + tx] = t[ty + i * 8][tx];
    }
}

// ---- pre-pass: b -> quantized fp32 ----
__global__ void pwb_quant_b(const float* __restrict__ b, float* __restrict__ bq, int n) {
    int i = blockIdx.x * blockDim.x + threadIdx.x;
    if (i < n) bq[i] = pwb_q(b[i]);
}

// ---- main GEMM: C[M][N] = relu(A[M][K]bf16 x Bt[N][K]bf16 + bq[N]) ----
__global__ __launch_bounds__(256) void pwb_gemm(
    const unsigned short* __restrict__ A,   // [M][K] bf16
    const unsigned short* __restrict__ Bt,  // [N][K] bf16
    const float* __restrict__ bq,           // [N]
    float* __restrict__ C,                  // [M][N] f32
    int M, int N, int K) {
    __shared__ unsigned short lA[BM * BK];  // 8 KB, swizzled k-chunks
    __shared__ unsigned short lB[BN * BK];  // 8 KB

    const int tid = threadIdx.x;
    const int w   = tid >> 6;
    const int l   = tid & 63;
    const int brow = blockIdx.y * BM;
    const int bcol = blockIdx.x * BN;
    const int wm = (w >> 1) * 64;   // wave row offset in tile
    const int wn = (w & 1) * 64;    // wave col offset in tile
    const int lr = l & 15;
    const int lk = l >> 4;

    // Staging: tile = 512 16B-chunks; chunk c -> row c>>2, k-chunk slot c&3.
    // Slot holds global k-chunk (slot ^ ((row>>1)&3))  [inverse-swizzled source,
    // linear LDS dest — required by global_load_lds].
    const int c0 = tid, c1 = tid + 256;
    const int r0 = c0 >> 2, kc0 = (c0 & 3) ^ ((r0 >> 1) & 3);
    const int r1 = c1 >> 2, kc1 = (c1 & 3) ^ ((r1 >> 1) & 3);

    const unsigned short* gA0 = A  + (size_t)(brow + r0) * K + kc0 * 8;
    const unsigned short* gA1 = A  + (size_t)(brow + r1) * K + kc1 * 8;
    const unsigned short* gB0 = Bt + (size_t)(bcol + r0) * K + kc0 * 8;
    const unsigned short* gB1 = Bt + (size_t)(bcol + r1) * K + kc1 * 8;

    unsigned short* lA0 = lA + (w * 64) * 8;          // wave-uniform LDS bases
    unsigned short* lA1 = lA + (256 + w * 64) * 8;
    unsigned short* lB0 = lB + (w * 64) * 8;
    unsigned short* lB1 = lB + (256 + w * 64) * 8;

    // ds_read offsets (ushort units): [row][k-chunk lk] with same XOR involution
    int offA[4], offB[4];
#pragma unroll
    for (int f = 0; f < 4; ++f) {
        int ra = wm + f * 16 + lr;
        offA[f] = ra * 32 + (lk ^ ((ra >> 1) & 3)) * 8;
        int rb = wn + f * 16 + lr;
        offB[f] = rb * 32 + (lk ^ ((rb >> 1) & 3)) * 8;
    }

    f32x4 acc[4][4] = {};

    for (int kt = 0; kt < K; kt += BK) {
        gload_lds16(gA0 + kt, lA0);
        gload_lds16(gA1 + kt, lA1);
        gload_lds16(gB0 + kt, lB0);
        gload_lds16(gB1 + kt, lB1);
        __syncthreads();              // drains vmcnt before barrier
        bf16x8 af[4], bf_[4];
#pragma unroll
        for (int f = 0; f < 4; ++f) af[f]  = *(const bf16x8*)&lA[offA[f]];
#pragma unroll
        for (int f = 0; f < 4; ++f) bf_[f] = *(const bf16x8*)&lB[offB[f]];
#pragma unroll
        for (int i = 0; i < 4; ++i)
#pragma unroll
            for (int j = 0; j < 4; ++j)
                acc[i][j] = __builtin_amdgcn_mfma_f32_16x16x32_bf16(
                    af[i], bf_[j], acc[i][j], 0, 0, 0);
        __syncthreads();              // protect LDS before next stage
    }

    // epilogue: bias + relu, C/D layout col=lane&15, row=(lane>>4)*4+reg (m89)
    float bias[4];
#pragma unroll
    for (int j = 0; j < 4; ++j) bias[j] = bq[bcol + wn + j * 16 + lr];

    const int orow = brow + wm + lk * 4;
    const int ocol = bcol + wn + lr;
#pragma unroll
    for (int i = 0; i < 4; ++i)
#pragma unroll
        for (int j = 0; j < 4; ++j)
#pragma unroll
            for (int r = 0; r < 4; ++r) {
                float v = acc[i][j][r] + bias[j];
                C[(size_t)(orow + i * 16 + r) * N + (ocol + j * 16)] = fmaxf(v, 0.f);
            }
}

// ---- fallback (any shape / tiny workspace): fp32, on-the-fly quantize ----
__global__ void pwb_fallback(const float* __restrict__ x, const float* __restrict__ W,
                             const float* __restrict__ b, float* __restrict__ out,
                             int M, int N, int K) {
    __shared__ float sA[16][17];
    __shared__ float sB[16][17];
    int tx = threadIdx.x, ty = threadIdx.y;
    int row = blockIdx.y * 16 + ty;
    int col = blockIdx.x * 16 + tx;
    float acc = 0.f;
    for (int kt = 0; kt < K; kt += 16) {
        sA[ty][tx] = (row < M && kt + tx < K) ? x[(size_t)row * K + kt + tx] : 0.f;
        float w = (kt + ty < K && col < N) ? W[(size_t)(kt + ty) * N + col] : 0.f;
        sB[ty][tx] = pwb_q(w);
        __syncthreads();
#pragma unroll
        for (int kk = 0; kk < 16; ++kk) acc += sA[ty][kk] * sB[kk][tx];
        __syncthreads();
    }
    if (row < M && col < N) {
        float v = acc + pwb_q(b[col]);
        out[(size_t)row * N + col] = fmaxf(v, 0.f);
    }
}

extern "C" void kernel_launch(void* const* d_in, const int* in_sizes, int n_in,
                              void* d_out, int out_size, void* d_ws, size_t ws_size,
                              hipStream_t stream) {
    const float* x = (const float*)d_in[0];
    const float* W = (const float*)d_in[1];
    const float* b = (const float*)d_in[2];
    float* out = (float*)d_out;

    const int DOUT = in_sizes[2];
    const int DIN  = in_sizes[1] / DOUT;
    const int M    = in_sizes[0] / DIN;

    size_t need = (size_t)M * DIN * 2 + (size_t)DIN * DOUT * 2 + (size_t)DOUT * 4;
    bool fast = (M % BM == 0) && (DOUT % BN == 0) && (DIN % BK == 0) &&
                (DIN % 32 == 0) && (DOUT % 32 == 0) && (ws_size >= need);

    if (fast) {
        unsigned short* xb = (unsigned short*)d_ws;            // [M][K] bf16
        unsigned short* Wt = xb + (size_t)M * DIN;             // [N][K] bf16
        float* bq = (float*)(Wt + (size_t)DIN * DOUT);         // [N] f32

        int n4 = (M * DIN) / 4;
        pwb_cvt_x<<<(n4 + 255) / 256, 256, 0, stream>>>((const float4*)x, (ushort4*)xb, n4);
        pwb_quant_w<<<dim3(DOUT / 32, DIN / 32), dim3(32, 8), 0, stream>>>(W, Wt, DIN, DOUT);
        pwb_quant_b<<<(DOUT + 255) / 256, 256, 0, stream>>>(b, bq, DOUT);
        pwb_gemm<<<dim3(DOUT / BN, M / BM), 256, 0, stream>>>(xb, Wt, bq, out, M, DOUT, DIN);
    } else {
        dim3 g((DOUT + 15) / 16, (M + 15) / 16), blk(16, 16);
        pwb_fallback<<<g, blk, 0, stream>>>(x, W, b, out, M, DOUT, DIN);
    }
}

// Round 3
// 58.528 us; speedup vs baseline: 1.2729x; 1.2729x over previous
//
#include <hip/hip_runtime.h>
#include <hip/hip_bf16.h>
#include <stdint.h>

// PWB linear layer: out = relu(x @ q(W) + q(b)), q = round(clip(t,-1,1)*127)/127
// R3: R2 structure with the fatal leftover-placeholder staging block REMOVED
// (it issued stray global_load_lds into lA[1]/lA[2] -> LDS write race ->
// nondeterministic replays). Deep-pipelined bf16 MFMA GEMM:
//   BM=256 BN=128 BK=64, 512 thr (8 waves, 4Mx2N, 64x64 per wave).
//   Triple-buffered LDS (144 KiB), 2-tile-deep prefetch, counted vmcnt(6)
//   (never drain to 0 in main loop), XOR chunk swizzle (conflict-free
//   ds_read_b128), s_setprio around MFMA clusters, bijective XCD swizzle.

typedef __attribute__((ext_vector_type(8))) short bf16x8;
typedef __attribute__((ext_vector_type(4))) float f32x4;

#define BM 256
#define BN 128
#define BK 64   // 8 x 16B chunks per row

__device__ __forceinline__ unsigned short f2b_rne(float f) {
    union { float f; uint32_t u; } v; v.f = f;
    uint32_t u = v.u;
    return (unsigned short)((u + 0x7FFFu + ((u >> 16) & 1u)) >> 16);
}

__device__ __forceinline__ float pwb_q(float w) {
    w = fminf(fmaxf(w, -1.f), 1.f);
    return rintf(w * 127.f) * (1.f / 127.f);   // rintf = RNE, matches jnp.round
}

__device__ __forceinline__ void gl16(const unsigned short* g, unsigned short* l) {
    __builtin_amdgcn_global_load_lds(
        (const __attribute__((address_space(1))) void*)(g),
        (__attribute__((address_space(3))) void*)(l),
        16, 0, 0);
}

#define WAIT_LGKM0 { asm volatile("s_waitcnt lgkmcnt(0)" ::: "memory"); \
                     __builtin_amdgcn_sched_barrier(0); }
#define WAIT_VM6   asm volatile("s_waitcnt vmcnt(6)" ::: "memory");
#define WAIT_VM0   asm volatile("s_waitcnt vmcnt(0)" ::: "memory");
#define BAR()      __builtin_amdgcn_s_barrier();

// ---- pre-pass: x fp32 -> bf16 ----
__global__ void pwb_cvt_x(const float4* __restrict__ x, ushort4* __restrict__ xb, int n4) {
    int i = blockIdx.x * blockDim.x + threadIdx.x;
    if (i < n4) {
        float4 v = x[i];
        xb[i] = make_ushort4(f2b_rne(v.x), f2b_rne(v.y), f2b_rne(v.z), f2b_rne(v.w));
    }
}

// ---- pre-pass: W[DIN][DOUT] fp32 -> quantized, transposed Wt[DOUT][DIN] bf16 ----
__global__ void pwb_quant_w(const float* __restrict__ W, unsigned short* __restrict__ Wt,
                            int DIN, int DOUT) {
    __shared__ unsigned short t[32][33];
    const int tx = threadIdx.x;     // 32
    const int ty = threadIdx.y;     // 8
    const int c0 = blockIdx.x * 32; // DOUT base
    const int r0 = blockIdx.y * 32; // DIN base
#pragma unroll
    for (int i = 0; i < 4; ++i) {
        int row = r0 + ty + i * 8;
        float w = W[(size_t)row * DOUT + c0 + tx];
        t[tx][ty + i * 8] = f2b_rne(pwb_q(w));
    }
    __syncthreads();
#pragma unroll
    for (int i = 0; i < 4; ++i) {
        int orow = c0 + ty + i * 8; // DOUT index
        Wt[(size_t)orow * DIN + r0 + tx] = t[ty + i * 8][tx];
    }
}

// ---- pre-pass: b -> quantized fp32 ----
__global__ void pwb_quant_b(const float* __restrict__ b, float* __restrict__ bq, int n) {
    int i = blockIdx.x * blockDim.x + threadIdx.x;
    if (i < n) bq[i] = pwb_q(b[i]);
}

// ================= main GEMM =================
// C[M][N] = relu(A[M][K]bf16 x Bt[N][K]bf16 + bq[N])
__global__ __launch_bounds__(512, 1) void pwb_gemm8(
    const unsigned short* __restrict__ A,   // [M][K] bf16
    const unsigned short* __restrict__ Bt,  // [N][K] bf16
    const float* __restrict__ bq,           // [N]
    float* __restrict__ C,                  // [M][N] f32
    int M, int N, int K, int GN, int nwg) {
    // triple-buffered tiles: A 32KB, B 16KB each -> 144 KiB total
    __shared__ __align__(16) unsigned short lA[3][BM * BK];
    __shared__ __align__(16) unsigned short lB[3][BN * BK];

    const int tid = threadIdx.x;
    const int w   = tid >> 6;     // 0..7
    const int l   = tid & 63;
    const int lr  = l & 15;
    const int lk  = l >> 4;       // 0..3

    // bijective XCD swizzle (m204): consecutive wgids share tm (A-panel in L2)
    const int bid = blockIdx.x;
    const int q = nwg >> 3, r = nwg & 7;
    const int xcd = bid & 7, lin = bid >> 3;
    const int wgid = (xcd < r ? xcd * (q + 1) : r * (q + 1) + (xcd - r) * q) + lin;
    const int tm = wgid / GN, tn = wgid % GN;
    const size_t brow = (size_t)tm * BM, bcol = (size_t)tn * BN;

    const int wm = (w >> 1) * 64;   // wave M offset (0..192)
    const int wn = (w & 1) * 64;    // wave N offset (0/64)

    // ---- staging source addrs (chunk s = tid + 512*i; row s>>3, slot s&7
    //      holds global k-chunk (s&7)^(row&7): inverse-swizzled source,
    //      linear LDS dest as required by global_load_lds) ----
    const unsigned short *gAp[4], *gBp[2];
#pragma unroll
    for (int i = 0; i < 4; ++i) {
        int s = tid + 512 * i, rr = s >> 3;
        int kc = (s & 7) ^ (rr & 7);
        gAp[i] = A + (size_t)(brow + rr) * K + kc * 8;
    }
#pragma unroll
    for (int i = 0; i < 2; ++i) {
        int s = tid + 512 * i, rr = s >> 3;
        int kc = (s & 7) ^ (rr & 7);
        gBp[i] = Bt + (size_t)(bcol + rr) * K + kc * 8;
    }

    // ---- ds_read offsets (ushort units), same XOR involution ----
    int offA[2][4], offB[2][4];
#pragma unroll
    for (int ks = 0; ks < 2; ++ks)
#pragma unroll
        for (int f = 0; f < 4; ++f) {
            int ra = wm + f * 16 + lr;
            offA[ks][f] = ra * 64 + ((4 * ks + lk) ^ (lr & 7)) * 8;
            int rb = wn + f * 16 + lr;
            offB[ks][f] = rb * 64 + ((4 * ks + lk) ^ (lr & 7)) * 8;
        }

    f32x4 acc[4][4] = {};

    const int T = K / BK;   // >= 2

#define DS_FRAGS(ks, cA, cB)                                  \
    bf16x8 af[4], bfr[4];                                     \
    _Pragma("unroll") for (int mi = 0; mi < 4; ++mi)          \
        af[mi] = *(const bf16x8*)&(cA)[offA[ks][mi]];         \
    _Pragma("unroll") for (int nj = 0; nj < 4; ++nj)          \
        bfr[nj] = *(const bf16x8*)&(cB)[offB[ks][nj]];

#define MFMA16                                                 \
    __builtin_amdgcn_s_setprio(1);                             \
    _Pragma("unroll") for (int mi = 0; mi < 4; ++mi)           \
    _Pragma("unroll") for (int nj = 0; nj < 4; ++nj)           \
        acc[mi][nj] = __builtin_amdgcn_mfma_f32_16x16x32_bf16( \
            af[mi], bfr[nj], acc[mi][nj], 0, 0, 0);            \
    __builtin_amdgcn_s_setprio(0);

    // ---- prologue: stage tiles 0 and 1 (exactly 12 loads per wave) ----
    {
        unsigned short* nA = &lA[0][0]; unsigned short* nB = &lB[0][0];
        gl16(gAp[0] + 0, nA + (0 * 512 + w * 64) * 8);
        gl16(gAp[1] + 0, nA + (1 * 512 + w * 64) * 8);
        gl16(gAp[2] + 0, nA + (2 * 512 + w * 64) * 8);
        gl16(gAp[3] + 0, nA + (3 * 512 + w * 64) * 8);
        gl16(gBp[0] + 0, nB + (0 * 512 + w * 64) * 8);
        gl16(gBp[1] + 0, nB + (1 * 512 + w * 64) * 8);
        unsigned short* mA = &lA[1][0]; unsigned short* mB = &lB[1][0];
        gl16(gAp[0] + BK, mA + (0 * 512 + w * 64) * 8);
        gl16(gAp[1] + BK, mA + (1 * 512 + w * 64) * 8);
        gl16(gAp[2] + BK, mA + (2 * 512 + w * 64) * 8);
        gl16(gAp[3] + BK, mA + (3 * 512 + w * 64) * 8);
        gl16(gBp[0] + BK, mB + (0 * 512 + w * 64) * 8);
        gl16(gBp[1] + BK, mB + (1 * 512 + w * 64) * 8);
    }
    WAIT_VM6        // tile 0 resident (tile 1 may still fly)
    BAR();

    int cur = 0;
    // ---- main loop: compute tile t, prefetch tile t+2 ----
    for (int t = 0; t < T - 2; ++t) {
        int nb = cur + 2; if (nb >= 3) nb -= 3;
        const unsigned short* cA = &lA[cur][0];
        const unsigned short* cB = &lB[cur][0];
        unsigned short* nA = &lA[nb][0];
        unsigned short* nB = &lB[nb][0];
        const int ktg = (t + 2) * BK;
        // phase 0: ds_read ks0 frags + stage 3 chunks
        {
            DS_FRAGS(0, cA, cB)
            gl16(gAp[0] + ktg, nA + (0 * 512 + w * 64) * 8);
            gl16(gAp[1] + ktg, nA + (1 * 512 + w * 64) * 8);
            gl16(gBp[0] + ktg, nB + (0 * 512 + w * 64) * 8);
            BAR();
            WAIT_LGKM0
            MFMA16
            BAR();
        }
        // phase 1: ds_read ks1 frags + stage 3 chunks
        {
            DS_FRAGS(1, cA, cB)
            gl16(gAp[2] + ktg, nA + (2 * 512 + w * 64) * 8);
            gl16(gAp[3] + ktg, nA + (3 * 512 + w * 64) * 8);
            gl16(gBp[1] + ktg, nB + (1 * 512 + w * 64) * 8);
            BAR();
            WAIT_LGKM0
            MFMA16
        }
        WAIT_VM6        // tile t+1 resident; tile t+2's 6 loads stay in flight
        BAR();
        cur = (cur == 2) ? 0 : cur + 1;
    }
    // ---- tail iter T-2: no prefetch, drain to 0 at end ----
    {
        const unsigned short* cA = &lA[cur][0];
        const unsigned short* cB = &lB[cur][0];
        { DS_FRAGS(0, cA, cB) BAR(); WAIT_LGKM0 MFMA16 BAR(); }
        { DS_FRAGS(1, cA, cB) BAR(); WAIT_LGKM0 MFMA16 }
        WAIT_VM0        // tile T-1 resident
        BAR();
        cur = (cur == 2) ? 0 : cur + 1;
    }
    // ---- tail iter T-1: compute only ----
    {
        const unsigned short* cA = &lA[cur][0];
        const unsigned short* cB = &lB[cur][0];
        { DS_FRAGS(0, cA, cB) WAIT_LGKM0 MFMA16 }
        { DS_FRAGS(1, cA, cB) WAIT_LGKM0 MFMA16 }
    }

    // ---- epilogue: bias + relu; C/D layout col=lane&15, row=(lane>>4)*4+reg ----
    float bias[4];
#pragma unroll
    for (int nj = 0; nj < 4; ++nj) bias[nj] = bq[bcol + wn + nj * 16 + lr];

    const size_t orow = brow + wm + lk * 4;
    const size_t ocol = bcol + wn + lr;
#pragma unroll
    for (int mi = 0; mi < 4; ++mi)
#pragma unroll
        for (int nj = 0; nj < 4; ++nj)
#pragma unroll
            for (int rg = 0; rg < 4; ++rg) {
                float v = acc[mi][nj][rg] + bias[nj];
                C[(orow + mi * 16 + rg) * N + (ocol + nj * 16)] = fmaxf(v, 0.f);
            }
#undef DS_FRAGS
#undef MFMA16
}

// ---- fallback (any shape): fp32, on-the-fly quantize ----
__global__ void pwb_fallback(const float* __restrict__ x, const float* __restrict__ W,
                             const float* __restrict__ b, float* __restrict__ out,
                             int M, int N, int K) {
    __shared__ float sA[16][17];
    __shared__ float sB[16][17];
    int tx = threadIdx.x, ty = threadIdx.y;
    int row = blockIdx.y * 16 + ty;
    int col = blockIdx.x * 16 + tx;
    float acc = 0.f;
    for (int kt = 0; kt < K; kt += 16) {
        sA[ty][tx] = (row < M && kt + tx < K) ? x[(size_t)row * K + kt + tx] : 0.f;
        float w = (kt + ty < K && col < N) ? W[(size_t)(kt + ty) * N + col] : 0.f;
        sB[ty][tx] = pwb_q(w);
        __syncthreads();
#pragma unroll
        for (int kk = 0; kk < 16; ++kk) acc += sA[ty][kk] * sB[kk][tx];
        __syncthreads();
    }
    if (row < M && col < N) {
        float v = acc + pwb_q(b[col]);
        out[(size_t)row * N + col] = fmaxf(v, 0.f);
    }
}

extern "C" void kernel_launch(void* const* d_in, const int* in_sizes, int n_in,
                              void* d_out, int out_size, void* d_ws, size_t ws_size,
                              hipStream_t stream) {
    const float* x = (const float*)d_in[0];
    const float* W = (const float*)d_in[1];
    const float* b = (const float*)d_in[2];
    float* out = (float*)d_out;

    const int DOUT = in_sizes[2];
    const int DIN  = in_sizes[1] / DOUT;
    const int M    = in_sizes[0] / DIN;

    size_t need = (size_t)M * DIN * 2 + (size_t)DIN * DOUT * 2 + (size_t)DOUT * 4;
    bool fast = (M % BM == 0) && (DOUT % BN == 0) && (DIN % BK == 0) &&
                (DIN >= 2 * BK) && (DIN % 32 == 0) && (DOUT % 32 == 0) &&
                (ws_size >= need);

    if (fast) {
        unsigned short* xb = (unsigned short*)d_ws;            // [M][K] bf16
        unsigned short* Wt = xb + (size_t)M * DIN;             // [N][K] bf16
        float* bq = (float*)(Wt + (size_t)DIN * DOUT);         // [N] f32

        int n4 = (M * DIN) / 4;
        pwb_cvt_x<<<(n4 + 255) / 256, 256, 0, stream>>>((const float4*)x, (ushort4*)xb, n4);
        pwb_quant_w<<<dim3(DOUT / 32, DIN / 32), dim3(32, 8), 0, stream>>>(W, Wt, DIN, DOUT);
        pwb_quant_b<<<(DOUT + 255) / 256, 256, 0, stream>>>(b, bq, DOUT);

        const int GM = M / BM, GN = DOUT / BN, nwg = GM * GN;
        pwb_gemm8<<<nwg, 512, 0, stream>>>(xb, Wt, bq, out, M, DOUT, DIN, GN, nwg);
    } else {
        dim3 g((DOUT + 15) / 16, (M + 15) / 16), blk(16, 16);
        pwb_fallback<<<g, blk, 0, stream>>>(x, W, b, out, M, DOUT, DIN);
    }
}

// Round 4
// 52.110 us; speedup vs baseline: 1.4297x; 1.1232x over previous
//
#include <hip/hip_runtime.h>
#include <hip/hip_bf16.h>
#include <stdint.h>

// PWB linear layer: out = relu(x @ q(W) + q(b)), q = round(clip(t,-1,1)*127)/127
// R4: i8 MFMA path. q(W) is EXACTLY k/127, k in [-127,127] -> store k as i8.
// x quantized per-row to i8 (xq = rint(x*127/rowmax)); accumulate exact i32 via
// mfma_i32_16x16x64_i8; epilogue: acc * (rowmax/127^2) + bq, relu.
// GEMM: BM=BN=128, BK=64, 4 waves (64x64/wave), 3-buffer pipeline, counted
// vmcnt(4), XOR chunk swizzle, grid=512 -> 2 blocks/CU for cross-block overlap.

typedef __attribute__((ext_vector_type(4))) int i32x4;

#define BM 128
#define BN 128
#define BK 64   // i8: 64 B per row per tile = 4 x 16B chunks

__device__ __forceinline__ float pwb_clip(float w) {
    return fminf(fmaxf(w, -1.f), 1.f);
}

__device__ __forceinline__ void gl16(const int8_t* g, int8_t* l) {
    __builtin_amdgcn_global_load_lds(
        (const __attribute__((address_space(1))) void*)(g),
        (__attribute__((address_space(3))) void*)(l),
        16, 0, 0);
}

#define WAIT_LGKM0 { asm volatile("s_waitcnt lgkmcnt(0)" ::: "memory"); \
                     __builtin_amdgcn_sched_barrier(0); }
#define WAIT_VM4   asm volatile("s_waitcnt vmcnt(4)" ::: "memory");
#define WAIT_VM0   asm volatile("s_waitcnt vmcnt(0)" ::: "memory");
#define BAR()      __builtin_amdgcn_s_barrier();

// ---- pre-pass: x fp32 -> per-row i8 (one wave per row; K%256==0) ----
__global__ void pwb_quant_x(const float* __restrict__ x, int8_t* __restrict__ xq,
                            float* __restrict__ scales, int K) {
    const int row = blockIdx.x * 4 + (threadIdx.x >> 6);
    const int l   = threadIdx.x & 63;
    const float4* xr = (const float4*)(x + (size_t)row * K);
    const int J = K >> 8;            // float4-groups per lane (K/256)
    float4 v[8];                     // supports K up to 2048
    float m = 0.f;
    for (int j = 0; j < J; ++j) {
        v[j] = xr[j * 64 + l];
        m = fmaxf(m, fmaxf(fmaxf(fabsf(v[j].x), fabsf(v[j].y)),
                           fmaxf(fabsf(v[j].z), fabsf(v[j].w))));
    }
#pragma unroll
    for (int d = 1; d < 64; d <<= 1) m = fmaxf(m, __shfl_xor(m, d));
    const float r = (m > 0.f) ? 127.f / m : 0.f;
    if (l == 0) scales[row] = m / 16129.f;     // rowmax / 127^2
    uint32_t* o = (uint32_t*)(xq + (size_t)row * K);
    for (int j = 0; j < J; ++j) {
        int q0 = (int)rintf(v[j].x * r), q1 = (int)rintf(v[j].y * r);
        int q2 = (int)rintf(v[j].z * r), q3 = (int)rintf(v[j].w * r);
        uint32_t u = (uint32_t)(q0 & 255) | ((uint32_t)(q1 & 255) << 8) |
                     ((uint32_t)(q2 & 255) << 16) | ((uint32_t)(q3 & 255) << 24);
        o[j * 64 + l] = u;
    }
}

// ---- pre-pass: W[DIN][DOUT] fp32 -> Wq[DOUT][DIN] i8 (k = rint(clip(w)*127)) ----
__global__ void pwb_quant_w(const float* __restrict__ W, int8_t* __restrict__ Wq,
                            int DIN, int DOUT) {
    __shared__ int8_t t[32][36];
    const int tx = threadIdx.x;     // 32
    const int ty = threadIdx.y;     // 8
    const int c0 = blockIdx.x * 32; // DOUT base
    const int r0 = blockIdx.y * 32; // DIN base
#pragma unroll
    for (int i = 0; i < 4; ++i) {
        int row = r0 + ty + i * 8;
        float w = W[(size_t)row * DOUT + c0 + tx];
        t[tx][ty + i * 8] = (int8_t)rintf(pwb_clip(w) * 127.f);
    }
    __syncthreads();
    // 256 threads: tt>>3 = local DOUT row (0..31), tt&7 = 4-byte word in DIN
    const int tt = ty * 32 + tx;
    const int lr = tt >> 3, wd = tt & 7;
    uint32_t u = (uint32_t)(uint8_t)t[lr][wd * 4 + 0]
               | ((uint32_t)(uint8_t)t[lr][wd * 4 + 1] << 8)
               | ((uint32_t)(uint8_t)t[lr][wd * 4 + 2] << 16)
               | ((uint32_t)(uint8_t)t[lr][wd * 4 + 3] << 24);
    ((uint32_t*)(Wq + (size_t)(c0 + lr) * DIN + r0))[wd] = u;
}

// ---- pre-pass: b -> quantized fp32 ----
__global__ void pwb_quant_b(const float* __restrict__ b, float* __restrict__ bq, int n) {
    int i = blockIdx.x * blockDim.x + threadIdx.x;
    if (i < n) bq[i] = rintf(pwb_clip(b[i]) * 127.f) * (1.f / 127.f);
}

// ================= main GEMM (i8) =================
// C[M][N] = relu( (A[M][K]i8 x Bt[N][K]i8) * scales[row] + bq[col] )
__global__ __launch_bounds__(256, 2) void pwb_gemmq(
    const int8_t* __restrict__ A,    // [M][K] i8
    const int8_t* __restrict__ Bt,   // [N][K] i8
    const float* __restrict__ scales,// [M] rowmax/127^2
    const float* __restrict__ bq,    // [N]
    float* __restrict__ C,           // [M][N] f32
    int M, int N, int K, int GN, int nwg) {
    // 3 buffers: A 8KB + B 8KB each -> 48 KiB total (2 blocks/CU)
    __shared__ __align__(16) int8_t lA[3][BM * BK];
    __shared__ __align__(16) int8_t lB[3][BN * BK];

    const int tid = threadIdx.x;
    const int w   = tid >> 6;     // 0..3
    const int l   = tid & 63;
    const int lr  = l & 15;
    const int lk  = l >> 4;       // 0..3 (k-chunk of 16 i8)

    // bijective XCD swizzle (m204)
    const int bid = blockIdx.x;
    const int q = nwg >> 3, r = nwg & 7;
    const int xcd = bid & 7, lin = bid >> 3;
    const int wgid = (xcd < r ? xcd * (q + 1) : r * (q + 1) + (xcd - r) * q) + lin;
    const int tm = wgid / GN, tn = wgid % GN;
    const size_t brow = (size_t)tm * BM, bcol = (size_t)tn * BN;

    const int wm = (w >> 1) * 64;   // wave M offset
    const int wn = (w & 1) * 64;    // wave N offset

    // ---- staging source addrs: chunk s = tid + 256*i (i=0,1); row = s>>2,
    //      slot = s&3 holds global k-chunk (s&3)^((s>>3)&3)  [inverse swizzle,
    //      linear LDS dest as global_load_lds requires] ----
    const int s0 = tid, s1 = tid + 256;
    const int r0c = s0 >> 2, k0c = (s0 & 3) ^ ((s0 >> 3) & 3);
    const int r1c = s1 >> 2, k1c = (s1 & 3) ^ ((s1 >> 3) & 3);
    const int8_t* gA0 = A  + (size_t)(brow + r0c) * K + k0c * 16;
    const int8_t* gA1 = A  + (size_t)(brow + r1c) * K + k1c * 16;
    const int8_t* gB0 = Bt + (size_t)(bcol + r0c) * K + k0c * 16;
    const int8_t* gB1 = Bt + (size_t)(bcol + r1c) * K + k1c * 16;

    // ---- ds_read byte offsets (row stride 64B; XOR involution on k-slot).
    //      row = wm|wn + f*16 + lr -> (row>>1)&3 == (lr>>1)&3 (wm,wn,f*16 are
    //      multiples of 16). frag f adds f*1024 (compile-time immediate). ----
    const int offAb = (wm + lr) * 64 + ((lk ^ ((lr >> 1) & 3)) << 4);
    const int offBb = (wn + lr) * 64 + ((lk ^ ((lr >> 1) & 3)) << 4);

    i32x4 acc[4][4] = {};

    const int T = K / BK;   // >= 2

#define STAGE(buf, ktg)                              \
    gl16(gA0 + (ktg), &lA[buf][w * 1024]);           \
    gl16(gA1 + (ktg), &lA[buf][w * 1024 + 4096]);    \
    gl16(gB0 + (ktg), &lB[buf][w * 1024]);           \
    gl16(gB1 + (ktg), &lB[buf][w * 1024 + 4096]);

#define DS_FRAGS(cA, cB)                                      \
    i32x4 af[4], bfr[4];                                      \
    _Pragma("unroll") for (int mi = 0; mi < 4; ++mi)          \
        af[mi] = *(const i32x4*)&(cA)[offAb + mi * 1024];     \
    _Pragma("unroll") for (int nj = 0; nj < 4; ++nj)          \
        bfr[nj] = *(const i32x4*)&(cB)[offBb + nj * 1024];

#define MFMA16                                                 \
    __builtin_amdgcn_s_setprio(1);                             \
    _Pragma("unroll") for (int mi = 0; mi < 4; ++mi)           \
    _Pragma("unroll") for (int nj = 0; nj < 4; ++nj)           \
        acc[mi][nj] = __builtin_amdgcn_mfma_i32_16x16x64_i8(   \
            af[mi], bfr[nj], acc[mi][nj], 0, 0, 0);            \
    __builtin_amdgcn_s_setprio(0);

    // ---- prologue: stage tiles 0,1 (8 loads/wave) ----
    STAGE(0, 0)
    STAGE(1, BK)
    WAIT_VM4        // tile 0 resident (tile 1's 4 still in flight)
    BAR();

    int cur = 0;
    // ---- main loop: compute tile t, prefetch tile t+2 ----
    for (int t = 0; t < T - 2; ++t) {
        int nb = cur + 2; if (nb >= 3) nb -= 3;
        const int8_t* cA = &lA[cur][0];
        const int8_t* cB = &lB[cur][0];
        {
            DS_FRAGS(cA, cB)
            STAGE(nb, (t + 2) * BK)
            BAR();
            WAIT_LGKM0
            MFMA16
        }
        WAIT_VM4    // tile t+1 resident; tile t+2's 4 loads stay in flight
        BAR();
        cur = (cur == 2) ? 0 : cur + 1;
    }
    // ---- tail iter T-2 ----
    {
        const int8_t* cA = &lA[cur][0];
        const int8_t* cB = &lB[cur][0];
        DS_FRAGS(cA, cB)
        BAR();
        WAIT_LGKM0
        MFMA16
        WAIT_VM0
        BAR();
        cur = (cur == 2) ? 0 : cur + 1;
    }
    // ---- tail iter T-1 ----
    {
        const int8_t* cA = &lA[cur][0];
        const int8_t* cB = &lB[cur][0];
        DS_FRAGS(cA, cB)
        WAIT_LGKM0
        MFMA16
    }

    // ---- epilogue: y = acc * scales[row] + bq[col], relu.
    //      C/D layout: col = lane&15, row = (lane>>4)*4 + reg ----
    float bias[4];
#pragma unroll
    for (int nj = 0; nj < 4; ++nj) bias[nj] = bq[bcol + wn + nj * 16 + lr];

    const size_t orow = brow + wm + lk * 4;
    const size_t ocol = bcol + wn + lr;
    float scl[4][4];
#pragma unroll
    for (int mi = 0; mi < 4; ++mi)
#pragma unroll
        for (int rg = 0; rg < 4; ++rg)
            scl[mi][rg] = scales[orow + mi * 16 + rg];

#pragma unroll
    for (int mi = 0; mi < 4; ++mi)
#pragma unroll
        for (int nj = 0; nj < 4; ++nj)
#pragma unroll
            for (int rg = 0; rg < 4; ++rg) {
                float v = fmaf((float)acc[mi][nj][rg], scl[mi][rg], bias[nj]);
                C[(orow + mi * 16 + rg) * N + (ocol + nj * 16)] = fmaxf(v, 0.f);
            }
#undef STAGE
#undef DS_FRAGS
#undef MFMA16
}

// ---- fallback (any shape): fp32, on-the-fly quantize ----
__global__ void pwb_fallback(const float* __restrict__ x, const float* __restrict__ W,
                             const float* __restrict__ b, float* __restrict__ out,
                             int M, int N, int K) {
    __shared__ float sA[16][17];
    __shared__ float sB[16][17];
    int tx = threadIdx.x, ty = threadIdx.y;
    int row = blockIdx.y * 16 + ty;
    int col = blockIdx.x * 16 + tx;
    float acc = 0.f;
    for (int kt = 0; kt < K; kt += 16) {
        sA[ty][tx] = (row < M && kt + tx < K) ? x[(size_t)row * K + kt + tx] : 0.f;
        float w = (kt + ty < K && col < N) ? W[(size_t)(kt + ty) * N + col] : 0.f;
        sB[ty][tx] = rintf(pwb_clip(w) * 127.f) * (1.f / 127.f);
        __syncthreads();
#pragma unroll
        for (int kk = 0; kk < 16; ++kk) acc += sA[ty][kk] * sB[kk][tx];
        __syncthreads();
    }
    if (row < M && col < N) {
        float v = acc + rintf(pwb_clip(b[col]) * 127.f) * (1.f / 127.f);
        out[(size_t)row * N + col] = fmaxf(v, 0.f);
    }
}

extern "C" void kernel_launch(void* const* d_in, const int* in_sizes, int n_in,
                              void* d_out, int out_size, void* d_ws, size_t ws_size,
                              hipStream_t stream) {
    const float* x = (const float*)d_in[0];
    const float* W = (const float*)d_in[1];
    const float* b = (const float*)d_in[2];
    float* out = (float*)d_out;

    const int DOUT = in_sizes[2];
    const int DIN  = in_sizes[1] / DOUT;
    const int M    = in_sizes[0] / DIN;

    size_t need = (size_t)M * DIN + (size_t)DIN * DOUT + (size_t)M * 4 + (size_t)DOUT * 4;
    bool fast = (M % BM == 0) && (M % 4 == 0) && (DOUT % BN == 0) &&
                (DIN % 256 == 0) && (DIN >= 2 * BK) && (DIN <= 2048) &&
                (DOUT % 32 == 0) && (DIN % 32 == 0) && (ws_size >= need);

    if (fast) {
        int8_t* xq = (int8_t*)d_ws;                       // [M][K] i8
        int8_t* Wq = xq + (size_t)M * DIN;                // [N][K] i8
        float* scales = (float*)(Wq + (size_t)DIN * DOUT);// [M] f32
        float* bq = scales + M;                           // [N] f32

        pwb_quant_x<<<M / 4, 256, 0, stream>>>(x, xq, scales, DIN);
        pwb_quant_w<<<dim3(DOUT / 32, DIN / 32), dim3(32, 8), 0, stream>>>(W, Wq, DIN, DOUT);
        pwb_quant_b<<<(DOUT + 255) / 256, 256, 0, stream>>>(b, bq, DOUT);

        const int GM = M / BM, GN = DOUT / BN, nwg = GM * GN;
        pwb_gemmq<<<nwg, 256, 0, stream>>>(xq, Wq, scales, bq, out, M, DOUT, DIN, GN, nwg);
    } else {
        dim3 g((DOUT + 15) / 16, (M + 15) / 16), blk(16, 16);
        pwb_fallback<<<g, blk, 0, stream>>>(x, W, b, out, M, DOUT, DIN);
    }
}

// Round 5
// 42.380 us; speedup vs baseline: 1.7580x; 1.2296x over previous
//
#include <hip/hip_runtime.h>
#include <hip/hip_bf16.h>
#include <stdint.h>

// PWB linear layer: out = relu(x @ q(W) + q(b)), q = round(clip(t,-1,1)*127)/127
// R5: R4 i8 path with quant_x scratch-spill fixed (two-pass row read, no
// per-lane array -> no runtime-indexed scratch; 2nd pass hits L1), and
// bias quantization folded into the GEMM epilogue (one fewer launch).
// GEMM unchanged: mfma_i32_16x16x64_i8, BM=BN=128, BK=64, 4 waves, 3-buffer
// pipeline, counted vmcnt(4), XOR chunk swizzle, 2 blocks/CU.

typedef __attribute__((ext_vector_type(4))) int i32x4;

#define BM 128
#define BN 128
#define BK 64   // i8: 64 B per row per tile = 4 x 16B chunks

__device__ __forceinline__ float pwb_clip(float w) {
    return fminf(fmaxf(w, -1.f), 1.f);
}

__device__ __forceinline__ void gl16(const int8_t* g, int8_t* l) {
    __builtin_amdgcn_global_load_lds(
        (const __attribute__((address_space(1))) void*)(g),
        (__attribute__((address_space(3))) void*)(l),
        16, 0, 0);
}

#define WAIT_LGKM0 { asm volatile("s_waitcnt lgkmcnt(0)" ::: "memory"); \
                     __builtin_amdgcn_sched_barrier(0); }
#define WAIT_VM4   asm volatile("s_waitcnt vmcnt(4)" ::: "memory");
#define WAIT_VM0   asm volatile("s_waitcnt vmcnt(0)" ::: "memory");
#define BAR()      __builtin_amdgcn_s_barrier();

// ---- pre-pass: x fp32 -> per-row i8, two-pass (no scratch arrays) ----
// one wave per row; requires K % 256 == 0
__global__ void pwb_quant_x(const float* __restrict__ x, int8_t* __restrict__ xq,
                            float* __restrict__ scales, int K) {
    const int row = blockIdx.x * 4 + (threadIdx.x >> 6);
    const int l   = threadIdx.x & 63;
    const float4* xr = (const float4*)(x + (size_t)row * K);
    const int J = K >> 8;            // float4-groups per lane
    float m = 0.f;
    for (int j = 0; j < J; ++j) {
        float4 v = xr[j * 64 + l];
        m = fmaxf(m, fmaxf(fmaxf(fabsf(v.x), fabsf(v.y)),
                           fmaxf(fabsf(v.z), fabsf(v.w))));
    }
#pragma unroll
    for (int d = 1; d < 64; d <<= 1) m = fmaxf(m, __shfl_xor(m, d));
    const float r = (m > 0.f) ? 127.f / m : 0.f;
    if (l == 0) scales[row] = m / 16129.f;     // rowmax / 127^2
    uint32_t* o = (uint32_t*)(xq + (size_t)row * K);
    for (int j = 0; j < J; ++j) {
        float4 v = xr[j * 64 + l];             // L1-hit (same wave just read it)
        int q0 = (int)rintf(v.x * r), q1 = (int)rintf(v.y * r);
        int q2 = (int)rintf(v.z * r), q3 = (int)rintf(v.w * r);
        uint32_t u = (uint32_t)(q0 & 255) | ((uint32_t)(q1 & 255) << 8) |
                     ((uint32_t)(q2 & 255) << 16) | ((uint32_t)(q3 & 255) << 24);
        o[j * 64 + l] = u;
    }
}

// ---- pre-pass: W[DIN][DOUT] fp32 -> Wq[DOUT][DIN] i8 (k = rint(clip(w)*127)) ----
__global__ void pwb_quant_w(const float* __restrict__ W, int8_t* __restrict__ Wq,
                            int DIN, int DOUT) {
    __shared__ int8_t t[32][36];
    const int tx = threadIdx.x;     // 32
    const int ty = threadIdx.y;     // 8
    const int c0 = blockIdx.x * 32; // DOUT base
    const int r0 = blockIdx.y * 32; // DIN base
#pragma unroll
    for (int i = 0; i < 4; ++i) {
        int row = r0 + ty + i * 8;
        float w = W[(size_t)row * DOUT + c0 + tx];
        t[tx][ty + i * 8] = (int8_t)rintf(pwb_clip(w) * 127.f);
    }
    __syncthreads();
    // 256 threads: tt>>3 = local DOUT row (0..31), tt&7 = 4-byte word in DIN
    const int tt = ty * 32 + tx;
    const int lr = tt >> 3, wd = tt & 7;
    uint32_t u = (uint32_t)(uint8_t)t[lr][wd * 4 + 0]
               | ((uint32_t)(uint8_t)t[lr][wd * 4 + 1] << 8)
               | ((uint32_t)(uint8_t)t[lr][wd * 4 + 2] << 16)
               | ((uint32_t)(uint8_t)t[lr][wd * 4 + 3] << 24);
    ((uint32_t*)(Wq + (size_t)(c0 + lr) * DIN + r0))[wd] = u;
}

// ================= main GEMM (i8) =================
// C[M][N] = relu( (A[M][K]i8 x Bt[N][K]i8) * scales[row] + q(b)[col] )
__global__ __launch_bounds__(256, 2) void pwb_gemmq(
    const int8_t* __restrict__ A,    // [M][K] i8
    const int8_t* __restrict__ Bt,   // [N][K] i8
    const float* __restrict__ scales,// [M] rowmax/127^2
    const float* __restrict__ b,     // [N] raw bias (quantized inline)
    float* __restrict__ C,           // [M][N] f32
    int M, int N, int K, int GN, int nwg) {
    // 3 buffers: A 8KB + B 8KB each -> 48 KiB total (2 blocks/CU)
    __shared__ __align__(16) int8_t lA[3][BM * BK];
    __shared__ __align__(16) int8_t lB[3][BN * BK];

    const int tid = threadIdx.x;
    const int w   = tid >> 6;     // 0..3
    const int l   = tid & 63;
    const int lr  = l & 15;
    const int lk  = l >> 4;       // 0..3 (k-chunk of 16 i8)

    // bijective XCD swizzle (m204)
    const int bid = blockIdx.x;
    const int q = nwg >> 3, r = nwg & 7;
    const int xcd = bid & 7, lin = bid >> 3;
    const int wgid = (xcd < r ? xcd * (q + 1) : r * (q + 1) + (xcd - r) * q) + lin;
    const int tm = wgid / GN, tn = wgid % GN;
    const size_t brow = (size_t)tm * BM, bcol = (size_t)tn * BN;

    const int wm = (w >> 1) * 64;   // wave M offset
    const int wn = (w & 1) * 64;    // wave N offset

    // ---- staging source addrs: chunk s = tid + 256*i (i=0,1); row = s>>2,
    //      slot = s&3 holds global k-chunk (s&3)^((s>>3)&3)  [inverse swizzle,
    //      linear LDS dest as global_load_lds requires] ----
    const int s0 = tid, s1 = tid + 256;
    const int r0c = s0 >> 2, k0c = (s0 & 3) ^ ((s0 >> 3) & 3);
    const int r1c = s1 >> 2, k1c = (s1 & 3) ^ ((s1 >> 3) & 3);
    const int8_t* gA0 = A  + (size_t)(brow + r0c) * K + k0c * 16;
    const int8_t* gA1 = A  + (size_t)(brow + r1c) * K + k1c * 16;
    const int8_t* gB0 = Bt + (size_t)(bcol + r0c) * K + k0c * 16;
    const int8_t* gB1 = Bt + (size_t)(bcol + r1c) * K + k1c * 16;

    // ---- ds_read byte offsets (row stride 64B; XOR involution on k-slot) ----
    const int offAb = (wm + lr) * 64 + ((lk ^ ((lr >> 1) & 3)) << 4);
    const int offBb = (wn + lr) * 64 + ((lk ^ ((lr >> 1) & 3)) << 4);

    i32x4 acc[4][4] = {};

    const int T = K / BK;   // >= 2

#define STAGE(buf, ktg)                              \
    gl16(gA0 + (ktg), &lA[buf][w * 1024]);           \
    gl16(gA1 + (ktg), &lA[buf][w * 1024 + 4096]);    \
    gl16(gB0 + (ktg), &lB[buf][w * 1024]);           \
    gl16(gB1 + (ktg), &lB[buf][w * 1024 + 4096]);

#define DS_FRAGS(cA, cB)                                      \
    i32x4 af[4], bfr[4];                                      \
    _Pragma("unroll") for (int mi = 0; mi < 4; ++mi)          \
        af[mi] = *(const i32x4*)&(cA)[offAb + mi * 1024];     \
    _Pragma("unroll") for (int nj = 0; nj < 4; ++nj)          \
        bfr[nj] = *(const i32x4*)&(cB)[offBb + nj * 1024];

#define MFMA16                                                 \
    __builtin_amdgcn_s_setprio(1);                             \
    _Pragma("unroll") for (int mi = 0; mi < 4; ++mi)           \
    _Pragma("unroll") for (int nj = 0; nj < 4; ++nj)           \
        acc[mi][nj] = __builtin_amdgcn_mfma_i32_16x16x64_i8(   \
            af[mi], bfr[nj], acc[mi][nj], 0, 0, 0);            \
    __builtin_amdgcn_s_setprio(0);

    // ---- prologue: stage tiles 0,1 (8 loads/wave) ----
    STAGE(0, 0)
    STAGE(1, BK)
    WAIT_VM4        // tile 0 resident (tile 1's 4 still in flight)
    BAR();

    int cur = 0;
    // ---- main loop: compute tile t, prefetch tile t+2 ----
    for (int t = 0; t < T - 2; ++t) {
        int nb = cur + 2; if (nb >= 3) nb -= 3;
        const int8_t* cA = &lA[cur][0];
        const int8_t* cB = &lB[cur][0];
        {
            DS_FRAGS(cA, cB)
            STAGE(nb, (t + 2) * BK)
            BAR();
            WAIT_LGKM0
            MFMA16
        }
        WAIT_VM4    // tile t+1 resident; tile t+2's 4 loads stay in flight
        BAR();
        cur = (cur == 2) ? 0 : cur + 1;
    }
    // ---- tail iter T-2 ----
    {
        const int8_t* cA = &lA[cur][0];
        const int8_t* cB = &lB[cur][0];
        DS_FRAGS(cA, cB)
        BAR();
        WAIT_LGKM0
        MFMA16
        WAIT_VM0
        BAR();
        cur = (cur == 2) ? 0 : cur + 1;
    }
    // ---- tail iter T-1 ----
    {
        const int8_t* cA = &lA[cur][0];
        const int8_t* cB = &lB[cur][0];
        DS_FRAGS(cA, cB)
        WAIT_LGKM0
        MFMA16
    }

    // ---- epilogue: y = acc * scales[row] + q(b)[col], relu.
    //      C/D layout: col = lane&15, row = (lane>>4)*4 + reg ----
    float bias[4];
#pragma unroll
    for (int nj = 0; nj < 4; ++nj) {
        float bv = b[bcol + wn + nj * 16 + lr];
        bias[nj] = rintf(pwb_clip(bv) * 127.f) * (1.f / 127.f);
    }

    const size_t orow = brow + wm + lk * 4;
    const size_t ocol = bcol + wn + lr;
    float scl[4][4];
#pragma unroll
    for (int mi = 0; mi < 4; ++mi)
#pragma unroll
        for (int rg = 0; rg < 4; ++rg)
            scl[mi][rg] = scales[orow + mi * 16 + rg];

#pragma unroll
    for (int mi = 0; mi < 4; ++mi)
#pragma unroll
        for (int nj = 0; nj < 4; ++nj)
#pragma unroll
            for (int rg = 0; rg < 4; ++rg) {
                float v = fmaf((float)acc[mi][nj][rg], scl[mi][rg], bias[nj]);
                C[(orow + mi * 16 + rg) * N + (ocol + nj * 16)] = fmaxf(v, 0.f);
            }
#undef STAGE
#undef DS_FRAGS
#undef MFMA16
}

// ---- fallback (any shape): fp32, on-the-fly quantize ----
__global__ void pwb_fallback(const float* __restrict__ x, const float* __restrict__ W,
                             const float* __restrict__ b, float* __restrict__ out,
                             int M, int N, int K) {
    __shared__ float sA[16][17];
    __shared__ float sB[16][17];
    int tx = threadIdx.x, ty = threadIdx.y;
    int row = blockIdx.y * 16 + ty;
    int col = blockIdx.x * 16 + tx;
    float acc = 0.f;
    for (int kt = 0; kt < K; kt += 16) {
        sA[ty][tx] = (row < M && kt + tx < K) ? x[(size_t)row * K + kt + tx] : 0.f;
        float w = (kt + ty < K && col < N) ? W[(size_t)(kt + ty) * N + col] : 0.f;
        sB[ty][tx] = rintf(pwb_clip(w) * 127.f) * (1.f / 127.f);
        __syncthreads();
#pragma unroll
        for (int kk = 0; kk < 16; ++kk) acc += sA[ty][kk] * sB[kk][tx];
        __syncthreads();
    }
    if (row < M && col < N) {
        float v = acc + rintf(pwb_clip(b[col]) * 127.f) * (1.f / 127.f);
        out[(size_t)row * N + col] = fmaxf(v, 0.f);
    }
}

extern "C" void kernel_launch(void* const* d_in, const int* in_sizes, int n_in,
                              void* d_out, int out_size, void* d_ws, size_t ws_size,
                              hipStream_t stream) {
    const float* x = (const float*)d_in[0];
    const float* W = (const float*)d_in[1];
    const float* b = (const float*)d_in[2];
    float* out = (float*)d_out;

    const int DOUT = in_sizes[2];
    const int DIN  = in_sizes[1] / DOUT;
    const int M    = in_sizes[0] / DIN;

    size_t need = (size_t)M * DIN + (size_t)DIN * DOUT + (size_t)M * 4;
    bool fast = (M % BM == 0) && (M % 4 == 0) && (DOUT % BN == 0) &&
                (DIN % 256 == 0) && (DIN >= 2 * BK) &&
                (DOUT % 32 == 0) && (DIN % 32 == 0) && (ws_size >= need);

    if (fast) {
        int8_t* xq = (int8_t*)d_ws;                       // [M][K] i8
        int8_t* Wq = xq + (size_t)M * DIN;                // [N][K] i8
        float* scales = (float*)(Wq + (size_t)DIN * DOUT);// [M] f32

        pwb_quant_x<<<M / 4, 256, 0, stream>>>(x, xq, scales, DIN);
        pwb_quant_w<<<dim3(DOUT / 32, DIN / 32), dim3(32, 8), 0, stream>>>(W, Wq, DIN, DOUT);

        const int GM = M / BM, GN = DOUT / BN, nwg = GM * GN;
        pwb_gemmq<<<nwg, 256, 0, stream>>>(xq, Wq, scales, b, out, M, DOUT, DIN, GN, nwg);
    } else {
        dim3 g((DOUT + 15) / 16, (M + 15) / 16), blk(16, 16);
        pwb_fallback<<<g, blk, 0, stream>>>(x, W, b, out, M, DOUT, DIN);
    }
}